// Round 15
// baseline (278.569 us; speedup 1.0000x reference)
//
#include <hip/hip_runtime.h>

#define NP   8192
#define BB   4
#define DIN  32
#define M0   32
#define M1   32
#define M2   64
#define CAP  80
#define CSTR 81            // candidate row stride (odd -> conflict-free)
#define KWV  16            // waves per knn block
#define SEG  (NP / KWV)    // 512 points per wave

__device__ __forceinline__ float lrelu(float x) { return fmaxf(x, 0.1f * x); }
__device__ __forceinline__ unsigned umin_(unsigned a, unsigned b) { return a < b ? a : b; }
__device__ __forceinline__ unsigned umax_(unsigned a, unsigned b) { return a > b ? a : b; }

// monotonic float->uint key (total order incl. negatives)
__device__ __forceinline__ unsigned fkey(float f) {
    unsigned b = __float_as_uint(f);
    return (b & 0x80000000u) ? ~b : (b | 0x80000000u);
}
__device__ __forceinline__ float funkey(unsigned k) {
    unsigned b = (k & 0x80000000u) ? (k & 0x7fffffffu) : ~k;
    return __uint_as_float(b);
}

// round-to-nearest-even f32 -> bf16 (as uint16 in low bits)
__device__ __forceinline__ unsigned bf16rn(float f) {
    unsigned u = __float_as_uint(f);
    unsigned r = (u >> 16) & 1u;
    return (u + 0x7fffu + r) >> 16;
}

// max with a DPP-permuted copy: full VALU rate, no DS pipe.
template<int CTRL>
__device__ __forceinline__ float fmax_dpp(float v) {
    int s = __builtin_amdgcn_update_dpp(0, __float_as_int(v), CTRL, 0xf, 0xf, true);
    return fmaxf(v, __int_as_float(s));
}

// ---------------------------------------------------------------------------
// Kernel 1: pack pts4 = (x,y,z,|p|^2), ptsS = (-2x,-2y,-2z,|p|^2) and
// feat = W0[:,3:] @ points stored as bf16 pairs. Block = 4 waves over the
// same 64 points; wave w computes outputs [8w, 8w+8).
// ---------------------------------------------------------------------------
__global__ __launch_bounds__(256) void prep_kernel(
    const float* __restrict__ xyz, const float* __restrict__ points,
    const float* __restrict__ W0, float4* __restrict__ pts4,
    float4* __restrict__ ptsS, unsigned* __restrict__ featb)
{
    const int tid  = threadIdx.x;
    const int w    = __builtin_amdgcn_readfirstlane(tid >> 6);  // 0..3
    const int lane = tid & 63;
    const int t    = blockIdx.x * 64 + lane;     // point id, 512 blocks
    const int b    = t >> 13;
    const int n    = t & (NP - 1);

    if (w == 0) {
        const float* xb = xyz + (size_t)b * 3 * NP;
        float x = xb[n], y = xb[NP + n], z = xb[2 * NP + n];
        float s = x * x + y * y + z * z;
        pts4[t] = make_float4(x, y, z, s);
        ptsS[t] = make_float4(-2.f * x, -2.f * y, -2.f * z, s);
    }

    const float* pb = points + (size_t)b * DIN * NP + n;
    float p[DIN];
#pragma unroll
    for (int c = 0; c < DIN; ++c) p[c] = pb[c * NP];

    uint4 outv;
    unsigned* ov = (unsigned*)&outv;
#pragma unroll
    for (int r = 0; r < 4; ++r) {
        int oe = w * 8 + 2 * r;
        float a0 = 0.f, a1 = 0.f;
#pragma unroll
        for (int c = 0; c < DIN; ++c) {
            a0 = fmaf(W0[oe * 35 + 3 + c], p[c], a0);
            a1 = fmaf(W0[(oe + 1) * 35 + 3 + c], p[c], a1);
        }
        ov[r] = bf16rn(a0) | (bf16rn(a1) << 16);
    }
    *(uint4*)(featb + (size_t)t * 16 + w * 4) = outv;
}

// ---------------------------------------------------------------------------
// Kernel 2: exact 16-NN via scalar-pipe query broadcast (r13 structure).
// Launched as TWO dispatches of 256 blocks (blk0 = 0, 256) so each half
// (~53us) drops below conv_kernel (~100us) and conv finally surfaces in the
// rocprof top-5 with full counters. Work is identical; blocks independent.
// ---------------------------------------------------------------------------
__global__ __launch_bounds__(1024, 4) void knn_kernel(const float4* __restrict__ pts4,
                                                      const float4* __restrict__ ptsS,
                                                      int* __restrict__ idxout,
                                                      int blk0)
{
    __shared__ unsigned skey[64 * 65];              // 16.6 KB class-min keys
    __shared__ float    sT[64];
    __shared__ int      scnt[64];
    __shared__ float    cand_t[64 * CSTR];          // 20.7 KB
    __shared__ int      cand_i[64 * CSTR];          // 20.7 KB

    const int tid  = threadIdx.x;
    const int w    = __builtin_amdgcn_readfirstlane(tid >> 6);
    const int lane = tid & 63;
    const int blk  = blk0 + blockIdx.x;    // 512 logical blocks over 2 launches
    const int b    = blk >> 7;
    const int n0   = (blk & 127) << 6;
    const int bn0  = b * NP;
    const float4* P  = pts4 + bn0;         // raw (queries, fallback)
    const float4* S  = ptsS + bn0;         // pre-scaled (scan points)
    const float4* Pq = P + n0;             // this block's 64 queries

    for (int i = tid; i < 64 * 65; i += 1024) skey[i] = 0xFFFFFFFFu;
    if (tid < 64) scnt[tid] = 0;
    __syncthreads();

    // ---- load my 8 pre-scaled points once (coalesced, register-resident) ----
    const int base = w * SEG;
    float4 sp[8];
#pragma unroll
    for (int j = 0; j < 8; ++j) sp[j] = S[base + j * 64 + lane];

    // ---- pass 1: chunks of 8 queries via s_load; min3-tree over 8 pts ----
#pragma unroll 1
    for (int qc = 0; qc < 8; ++qc) {
        float4 qv[8];
#pragma unroll
        for (int i = 0; i < 8; ++i) qv[i] = Pq[qc * 8 + i];   // uniform -> s_load
#pragma unroll
        for (int i = 0; i < 8; ++i) {
            const float qx = qv[i].x, qy = qv[i].y, qz = qv[i].z;
            float t[8];
#pragma unroll
            for (int j = 0; j < 8; ++j)
                t[j] = fmaf(qx, sp[j].x, fmaf(qy, sp[j].y, fmaf(qz, sp[j].z, sp[j].w)));
            float a = fminf(fminf(t[0], t[1]), t[2]);   // v_min3
            float b2 = fminf(fminf(t[3], t[4]), t[5]);  // v_min3
            float c2 = fminf(fminf(t[6], t[7]), a);     // v_min3
            float mn = fminf(b2, c2);
            atomicMin(&skey[(qc * 8 + i) * 65 + lane], fkey(mn));
        }
    }
    __syncthreads();

    // ---- threshold: 16th smallest of the 64 class minima (thread = query) ----
    if (tid < 64) {
        unsigned t16[16];
#pragma unroll
        for (int i = 0; i < 16; ++i) t16[i] = 0xFFFFFFFFu;
        for (int c = 0; c < 64; ++c) {
            unsigned d = skey[tid * 65 + c];
            if (d < t16[15]) {
                t16[15] = d;
#pragma unroll
                for (int i = 15; i > 0; --i) {
                    unsigned a = t16[i - 1], cc = t16[i];
                    t16[i - 1] = umin_(a, cc);
                    t16[i]     = umax_(a, cc);
                }
            }
        }
        sT[tid] = funkey(t16[15]);
    }
    __syncthreads();

    // ---- pass 2: bit-identical recompute, per-point t<=T append ----
#pragma unroll 1
    for (int qc = 0; qc < 8; ++qc) {
        float4 qv[8];
#pragma unroll
        for (int i = 0; i < 8; ++i) qv[i] = Pq[qc * 8 + i];   // uniform -> s_load
#pragma unroll
        for (int i = 0; i < 8; ++i) {
            const int q = qc * 8 + i;
            const float qx = qv[i].x, qy = qv[i].y, qz = qv[i].z;
            const float T = sT[q];
#pragma unroll
            for (int j = 0; j < 8; ++j) {
                float t = fmaf(qx, sp[j].x, fmaf(qy, sp[j].y, fmaf(qz, sp[j].z, sp[j].w)));
                if (t <= T) {                        // ~16% wave-prob per point
                    int pos = atomicAdd(&scnt[q], 1);
                    if (pos < CAP) {
                        cand_t[q * CSTR + pos] = t;
                        cand_i[q * CSTR + pos] = base + j * 64 + lane;
                    }
                }
            }
        }
    }
    __syncthreads();

    // ---- exact selection among candidates (thread = query) ----
    if (tid < 64) {
        int cnt = scnt[tid];
        int* outp = idxout + ((bn0 + n0 + tid) << 4);
        float bd[16]; int bi[16];
#pragma unroll
        for (int i = 0; i < 16; ++i) { bd[i] = 3e38f; bi[i] = 0; }
        if (cnt <= CAP) {
            for (int pos = 0; pos < cnt; ++pos) {
                float d = cand_t[tid * CSTR + pos];
                int   j = cand_i[tid * CSTR + pos];
                if ((d < bd[15]) || (d == bd[15] && j < bi[15])) {
                    bd[15] = d; bi[15] = j;
#pragma unroll
                    for (int i = 15; i > 0; --i) {
                        bool sw = (bd[i] < bd[i - 1]) || (bd[i] == bd[i - 1] && bi[i] < bi[i - 1]);
                        float td = bd[i - 1]; int tj = bi[i - 1];
                        bd[i - 1] = sw ? bd[i] : td;  bi[i - 1] = sw ? bi[i] : tj;
                        bd[i]     = sw ? td : bd[i];  bi[i]     = sw ? tj : bi[i];
                    }
                }
            }
        } else {
            // overflow fallback (exact, never expected): identical fma form
            float4 q4 = Pq[tid];
            for (int j = 0; j < NP; ++j) {
                float4 s = S[j];
                float d = fmaf(q4.x, s.x, fmaf(q4.y, s.y, fmaf(q4.z, s.z, s.w)));
                if ((d < bd[15]) || (d == bd[15] && j < bi[15])) {
                    bd[15] = d; bi[15] = j;
#pragma unroll
                    for (int i = 15; i > 0; --i) {
                        bool sw = (bd[i] < bd[i - 1]) || (bd[i] == bd[i - 1] && bi[i] < bi[i - 1]);
                        float td = bd[i - 1]; int tj = bi[i - 1];
                        bd[i - 1] = sw ? bd[i] : td;  bi[i - 1] = sw ? bi[i] : tj;
                        bd[i]     = sw ? td : bd[i];  bi[i]     = sw ? tj : bi[i];
                    }
                }
            }
        }
#pragma unroll
        for (int i = 0; i < 16; ++i) outp[i] = bi[i];
    }
}

// ---------------------------------------------------------------------------
// Kernel 3: gather + conv0/1/2 + max over K. One thread per (n,k) column.
// __launch_bounds__(256) with NO min-wave cap: the previous (256,4) pinned
// VGPR<=128; if the true live set exceeds that, the compiler silently spills
// to scratch (the exact knn r6-r8 catastrophe) — conv's counters were never
// captured to rule this out. Letting the allocator float (up to 256 VGPR,
// >=2 waves/EU) removes any spill at modest occupancy cost.
// ---------------------------------------------------------------------------
__global__ __launch_bounds__(256) void conv_kernel(
    const float4* __restrict__ pts4, const unsigned* __restrict__ featb,
    const int* __restrict__ idx,
    const float* __restrict__ W0, const float* __restrict__ W1, const float* __restrict__ W2,
    float* __restrict__ out)
{
    __shared__ float so[M2][17];
    const int tid = threadIdx.x;
    const int k   = tid & 15;
    const int nl  = tid >> 4;              // 0..15
    const int blk = blockIdx.x;            // 2048 blocks
    const int b   = blk >> 9;              // 512 blocks per batch
    const int n0  = (blk & 511) << 4;
    const int n   = n0 + nl;
    const int bn  = b * NP + n;
    const int j   = idx[(bn << 4) + k];
    const int bj  = b * NP + j;

    const float4 pc = pts4[bn];
    const float4 pj = pts4[bj];
    const float rx = pj.x - pc.x, ry = pj.y - pc.y, rz = pj.z - pc.z;

    const uint4* fj = (const uint4*)(featb + (size_t)bj * 16);

    float x0[M0];
#pragma unroll
    for (int g = 0; g < 4; ++g) {
        uint4 u = fj[g];
        const unsigned* uv = (const unsigned*)&u;
#pragma unroll
        for (int r = 0; r < 4; ++r) {
            int o = g * 8 + 2 * r;
            float fe  = __uint_as_float(uv[r] << 16);
            float fo_ = __uint_as_float(uv[r] & 0xffff0000u);
            x0[o]     = lrelu(fmaf(W0[o * 35], rx, fmaf(W0[o * 35 + 1], ry, fmaf(W0[o * 35 + 2], rz, fe))));
            x0[o + 1] = lrelu(fmaf(W0[(o + 1) * 35], rx, fmaf(W0[(o + 1) * 35 + 1], ry, fmaf(W0[(o + 1) * 35 + 2], rz, fo_))));
        }
    }

    float x1[M1];
#pragma unroll
    for (int o = 0; o < M1; ++o) {
        float acc = 0.f;
#pragma unroll
        for (int c = 0; c < M0; ++c) acc = fmaf(W1[o * 32 + c], x0[c], acc);
        x1[o] = lrelu(acc);
    }

#pragma unroll
    for (int o = 0; o < M2; ++o) {
        float acc = 0.f;
#pragma unroll
        for (int c = 0; c < M1; ++c) acc = fmaf(W2[o * 32 + c], x1[c], acc);
        float v = lrelu(acc);
        // 16-lane max reduce via DPP (VALU-rate, no DS):
        v = fmax_dpp<0xB1>(v);    // quad_perm xor1
        v = fmax_dpp<0x4E>(v);    // quad_perm xor2
        v = fmax_dpp<0x141>(v);   // row_half_mirror
        v = fmax_dpp<0x140>(v);   // row_mirror
        if (k == (o & 15)) so[o][nl] = v;
    }
    __syncthreads();
    {
        int o = tid >> 2;                 // 0..63
        int col = (tid & 3) << 2;         // 0,4,8,12
        float4 v = make_float4(so[o][col], so[o][col + 1], so[o][col + 2], so[o][col + 3]);
        *(float4*)(out + ((size_t)(b * M2 + o)) * NP + n0 + col) = v;
    }
}

// ---------------------------------------------------------------------------
extern "C" void kernel_launch(void* const* d_in, const int* in_sizes, int n_in,
                              void* d_out, int out_size, void* d_ws, size_t ws_size,
                              hipStream_t stream)
{
    const float* xyz    = (const float*)d_in[0];
    const float* points = (const float*)d_in[1];
    const float* W0     = (const float*)d_in[2];
    const float* W1     = (const float*)d_in[3];
    const float* W2     = (const float*)d_in[4];
    float* out = (float*)d_out;

    char* ws = (char*)d_ws;
    float4*   pts4  = (float4*)ws;                       // 512 KB
    float4*   ptsS  = (float4*)(ws + 0x080000);          // 512 KB (pre-scaled)
    unsigned* featb = (unsigned*)(ws + 0x100000);        // 2 MB
    int*      idx   = (int*)(ws + 0x300000);             // 2 MB

    prep_kernel<<<BB * NP / 64, 256,  0, stream>>>(xyz, points, W0, pts4, ptsS, featb);
    knn_kernel <<<256, 1024, 0, stream>>>(pts4, ptsS, idx, 0);
    knn_kernel <<<256, 1024, 0, stream>>>(pts4, ptsS, idx, 256);
    conv_kernel<<<BB * NP / 16, 256,  0, stream>>>(pts4, featb, idx, W0, W1, W2, out);
}

// Round 16
// 241.056 us; speedup vs baseline: 1.1556x; 1.1556x over previous
//
#include <hip/hip_runtime.h>

#define NP   8192
#define BB   4
#define DIN  32
#define M0   32
#define M1   32
#define M2   64
#define CAP  80
#define CSTR 81            // candidate row stride (odd -> conflict-free)
#define KWV  16            // waves per knn block
#define SEG  (NP / KWV)    // 512 points per wave

__device__ __forceinline__ float lrelu(float x) { return fmaxf(x, 0.1f * x); }
__device__ __forceinline__ unsigned umin_(unsigned a, unsigned b) { return a < b ? a : b; }
__device__ __forceinline__ unsigned umax_(unsigned a, unsigned b) { return a > b ? a : b; }

// monotonic float->uint key (total order incl. negatives)
__device__ __forceinline__ unsigned fkey(float f) {
    unsigned b = __float_as_uint(f);
    return (b & 0x80000000u) ? ~b : (b | 0x80000000u);
}
__device__ __forceinline__ float funkey(unsigned k) {
    unsigned b = (k & 0x80000000u) ? (k & 0x7fffffffu) : ~k;
    return __uint_as_float(b);
}

// round-to-nearest-even f32 -> bf16 (as uint16 in low bits)
__device__ __forceinline__ unsigned bf16rn(float f) {
    unsigned u = __float_as_uint(f);
    unsigned r = (u >> 16) & 1u;
    return (u + 0x7fffu + r) >> 16;
}

// max with a DPP-permuted copy: full VALU rate, no DS pipe. Row-local ops
// (quad_perm / half-mirror / mirror) -> correct 16-lane reduce for any
// aligned 16-lane group.
template<int CTRL>
__device__ __forceinline__ float fmax_dpp(float v) {
    int s = __builtin_amdgcn_update_dpp(0, __float_as_int(v), CTRL, 0xf, 0xf, true);
    return fmaxf(v, __int_as_float(s));
}

// ---------------------------------------------------------------------------
// Kernel 1: pack pts4 = (x,y,z,|p|^2), ptsS = (-2x,-2y,-2z,|p|^2) and
// feat = W0[:,3:] @ points stored as bf16 pairs. Block = 4 waves over the
// same 64 points; wave w computes outputs [8w, 8w+8).
// ---------------------------------------------------------------------------
__global__ __launch_bounds__(256) void prep_kernel(
    const float* __restrict__ xyz, const float* __restrict__ points,
    const float* __restrict__ W0, float4* __restrict__ pts4,
    float4* __restrict__ ptsS, unsigned* __restrict__ featb)
{
    const int tid  = threadIdx.x;
    const int w    = __builtin_amdgcn_readfirstlane(tid >> 6);  // 0..3
    const int lane = tid & 63;
    const int t    = blockIdx.x * 64 + lane;     // point id, 512 blocks
    const int b    = t >> 13;
    const int n    = t & (NP - 1);

    if (w == 0) {
        const float* xb = xyz + (size_t)b * 3 * NP;
        float x = xb[n], y = xb[NP + n], z = xb[2 * NP + n];
        float s = x * x + y * y + z * z;
        pts4[t] = make_float4(x, y, z, s);
        ptsS[t] = make_float4(-2.f * x, -2.f * y, -2.f * z, s);
    }

    const float* pb = points + (size_t)b * DIN * NP + n;
    float p[DIN];
#pragma unroll
    for (int c = 0; c < DIN; ++c) p[c] = pb[c * NP];

    uint4 outv;
    unsigned* ov = (unsigned*)&outv;
#pragma unroll
    for (int r = 0; r < 4; ++r) {
        int oe = w * 8 + 2 * r;
        float a0 = 0.f, a1 = 0.f;
#pragma unroll
        for (int c = 0; c < DIN; ++c) {
            a0 = fmaf(W0[oe * 35 + 3 + c], p[c], a0);
            a1 = fmaf(W0[(oe + 1) * 35 + 3 + c], p[c], a1);
        }
        ov[r] = bf16rn(a0) | (bf16rn(a1) << 16);
    }
    *(uint4*)(featb + (size_t)t * 16 + w * 4) = outv;
}

// ---------------------------------------------------------------------------
// Kernel 2: exact 16-NN via scalar-pipe query broadcast. SINGLE 512-block
// dispatch (r15's 2x256 split proved knn is intra-block latency-bound:
// 95us/half vs 105 for the whole — the split cost ~85us total; reverted).
// lane = point; 8 pre-scaled points/lane in registers; queries s_loaded in
// chunks of 8, fed to v_fma as SGPR operands.
// ---------------------------------------------------------------------------
__global__ __launch_bounds__(1024, 4) void knn_kernel(const float4* __restrict__ pts4,
                                                      const float4* __restrict__ ptsS,
                                                      int* __restrict__ idxout)
{
    __shared__ unsigned skey[64 * 65];              // 16.6 KB class-min keys
    __shared__ float    sT[64];
    __shared__ int      scnt[64];
    __shared__ float    cand_t[64 * CSTR];          // 20.7 KB
    __shared__ int      cand_i[64 * CSTR];          // 20.7 KB

    const int tid  = threadIdx.x;
    const int w    = __builtin_amdgcn_readfirstlane(tid >> 6);
    const int lane = tid & 63;
    const int blk  = blockIdx.x;           // 512 blocks
    const int b    = blk >> 7;
    const int n0   = (blk & 127) << 6;
    const int bn0  = b * NP;
    const float4* P  = pts4 + bn0;         // raw (queries, fallback)
    const float4* S  = ptsS + bn0;         // pre-scaled (scan points)
    const float4* Pq = P + n0;             // this block's 64 queries

    for (int i = tid; i < 64 * 65; i += 1024) skey[i] = 0xFFFFFFFFu;
    if (tid < 64) scnt[tid] = 0;
    __syncthreads();

    // ---- load my 8 pre-scaled points once (coalesced, register-resident) ----
    const int base = w * SEG;
    float4 sp[8];
#pragma unroll
    for (int j = 0; j < 8; ++j) sp[j] = S[base + j * 64 + lane];

    // ---- pass 1: chunks of 8 queries via s_load; min3-tree over 8 pts ----
#pragma unroll 1
    for (int qc = 0; qc < 8; ++qc) {
        float4 qv[8];
#pragma unroll
        for (int i = 0; i < 8; ++i) qv[i] = Pq[qc * 8 + i];   // uniform -> s_load
#pragma unroll
        for (int i = 0; i < 8; ++i) {
            const float qx = qv[i].x, qy = qv[i].y, qz = qv[i].z;
            float t[8];
#pragma unroll
            for (int j = 0; j < 8; ++j)
                t[j] = fmaf(qx, sp[j].x, fmaf(qy, sp[j].y, fmaf(qz, sp[j].z, sp[j].w)));
            float a = fminf(fminf(t[0], t[1]), t[2]);   // v_min3
            float b2 = fminf(fminf(t[3], t[4]), t[5]);  // v_min3
            float c2 = fminf(fminf(t[6], t[7]), a);     // v_min3
            float mn = fminf(b2, c2);
            atomicMin(&skey[(qc * 8 + i) * 65 + lane], fkey(mn));
        }
    }
    __syncthreads();

    // ---- threshold: 16th smallest of the 64 class minima (thread = query) ----
    if (tid < 64) {
        unsigned t16[16];
#pragma unroll
        for (int i = 0; i < 16; ++i) t16[i] = 0xFFFFFFFFu;
        for (int c = 0; c < 64; ++c) {
            unsigned d = skey[tid * 65 + c];
            if (d < t16[15]) {
                t16[15] = d;
#pragma unroll
                for (int i = 15; i > 0; --i) {
                    unsigned a = t16[i - 1], cc = t16[i];
                    t16[i - 1] = umin_(a, cc);
                    t16[i]     = umax_(a, cc);
                }
            }
        }
        sT[tid] = funkey(t16[15]);
    }
    __syncthreads();

    // ---- pass 2: bit-identical recompute, per-point t<=T append ----
#pragma unroll 1
    for (int qc = 0; qc < 8; ++qc) {
        float4 qv[8];
#pragma unroll
        for (int i = 0; i < 8; ++i) qv[i] = Pq[qc * 8 + i];   // uniform -> s_load
#pragma unroll
        for (int i = 0; i < 8; ++i) {
            const int q = qc * 8 + i;
            const float qx = qv[i].x, qy = qv[i].y, qz = qv[i].z;
            const float T = sT[q];
#pragma unroll
            for (int j = 0; j < 8; ++j) {
                float t = fmaf(qx, sp[j].x, fmaf(qy, sp[j].y, fmaf(qz, sp[j].z, sp[j].w)));
                if (t <= T) {                        // ~16% wave-prob per point
                    int pos = atomicAdd(&scnt[q], 1);
                    if (pos < CAP) {
                        cand_t[q * CSTR + pos] = t;
                        cand_i[q * CSTR + pos] = base + j * 64 + lane;
                    }
                }
            }
        }
    }
    __syncthreads();

    // ---- exact selection among candidates (thread = query) ----
    if (tid < 64) {
        int cnt = scnt[tid];
        int* outp = idxout + ((bn0 + n0 + tid) << 4);
        float bd[16]; int bi[16];
#pragma unroll
        for (int i = 0; i < 16; ++i) { bd[i] = 3e38f; bi[i] = 0; }
        if (cnt <= CAP) {
            for (int pos = 0; pos < cnt; ++pos) {
                float d = cand_t[tid * CSTR + pos];
                int   j = cand_i[tid * CSTR + pos];
                if ((d < bd[15]) || (d == bd[15] && j < bi[15])) {
                    bd[15] = d; bi[15] = j;
#pragma unroll
                    for (int i = 15; i > 0; --i) {
                        bool sw = (bd[i] < bd[i - 1]) || (bd[i] == bd[i - 1] && bi[i] < bi[i - 1]);
                        float td = bd[i - 1]; int tj = bi[i - 1];
                        bd[i - 1] = sw ? bd[i] : td;  bi[i - 1] = sw ? bi[i] : tj;
                        bd[i]     = sw ? td : bd[i];  bi[i]     = sw ? tj : bi[i];
                    }
                }
            }
        } else {
            // overflow fallback (exact, never expected): identical fma form
            float4 q4 = Pq[tid];
            for (int j = 0; j < NP; ++j) {
                float4 s = S[j];
                float d = fmaf(q4.x, s.x, fmaf(q4.y, s.y, fmaf(q4.z, s.z, s.w)));
                if ((d < bd[15]) || (d == bd[15] && j < bi[15])) {
                    bd[15] = d; bi[15] = j;
#pragma unroll
                    for (int i = 15; i > 0; --i) {
                        bool sw = (bd[i] < bd[i - 1]) || (bd[i] == bd[i - 1] && bi[i] < bi[i - 1]);
                        float td = bd[i - 1]; int tj = bi[i - 1];
                        bd[i - 1] = sw ? bd[i] : td;  bi[i - 1] = sw ? bi[i] : tj;
                        bd[i]     = sw ? td : bd[i];  bi[i]     = sw ? tj : bi[i];
                    }
                }
            }
        }
#pragma unroll
        for (int i = 0; i < 16; ++i) outp[i] = bi[i];
    }
}

// ---------------------------------------------------------------------------
// Kernel 3: gather + conv0/1/2 + max over K. One thread per (n,k) column,
// 512-thread blocks (32 n x 16 k), 1024 blocks — r15 counters show conv is
// VALU-bound (VALUBusy 73%, no spill, VGPR 36); doubling waves/block trims
// per-block barrier/tail exposure. No __launch_bounds__ min-wave arg (the
// (256,4) cap cost ~30% in r14).
// ---------------------------------------------------------------------------
__global__ __launch_bounds__(512) void conv_kernel(
    const float4* __restrict__ pts4, const unsigned* __restrict__ featb,
    const int* __restrict__ idx,
    const float* __restrict__ W0, const float* __restrict__ W1, const float* __restrict__ W2,
    float* __restrict__ out)
{
    __shared__ float so[M2][33];
    const int tid = threadIdx.x;
    const int k   = tid & 15;
    const int nl  = tid >> 4;              // 0..31
    const int blk = blockIdx.x;            // 1024 blocks
    const int b   = blk >> 8;              // 256 blocks per batch
    const int n0  = (blk & 255) << 5;
    const int n   = n0 + nl;
    const int bn  = b * NP + n;
    const int j   = idx[(bn << 4) + k];
    const int bj  = b * NP + j;

    const float4 pc = pts4[bn];
    const float4 pj = pts4[bj];
    const float rx = pj.x - pc.x, ry = pj.y - pc.y, rz = pj.z - pc.z;

    const uint4* fj = (const uint4*)(featb + (size_t)bj * 16);

    float x0[M0];
#pragma unroll
    for (int g = 0; g < 4; ++g) {
        uint4 u = fj[g];
        const unsigned* uv = (const unsigned*)&u;
#pragma unroll
        for (int r = 0; r < 4; ++r) {
            int o = g * 8 + 2 * r;
            float fe  = __uint_as_float(uv[r] << 16);
            float fo_ = __uint_as_float(uv[r] & 0xffff0000u);
            x0[o]     = lrelu(fmaf(W0[o * 35], rx, fmaf(W0[o * 35 + 1], ry, fmaf(W0[o * 35 + 2], rz, fe))));
            x0[o + 1] = lrelu(fmaf(W0[(o + 1) * 35], rx, fmaf(W0[(o + 1) * 35 + 1], ry, fmaf(W0[(o + 1) * 35 + 2], rz, fo_))));
        }
    }

    float x1[M1];
#pragma unroll
    for (int o = 0; o < M1; ++o) {
        float acc = 0.f;
#pragma unroll
        for (int c = 0; c < M0; ++c) acc = fmaf(W1[o * 32 + c], x0[c], acc);
        x1[o] = lrelu(acc);
    }

#pragma unroll
    for (int o = 0; o < M2; ++o) {
        float acc = 0.f;
#pragma unroll
        for (int c = 0; c < M1; ++c) acc = fmaf(W2[o * 32 + c], x1[c], acc);
        float v = lrelu(acc);
        // 16-lane max reduce via DPP (VALU-rate, no DS):
        v = fmax_dpp<0xB1>(v);    // quad_perm xor1
        v = fmax_dpp<0x4E>(v);    // quad_perm xor2
        v = fmax_dpp<0x141>(v);   // row_half_mirror
        v = fmax_dpp<0x140>(v);   // row_mirror
        if (k == (o & 15)) so[o][nl] = v;
    }
    __syncthreads();
    {
        int o = tid >> 3;                 // 0..63
        int col = (tid & 7) << 2;         // 0..28
        float4 v = make_float4(so[o][col], so[o][col + 1], so[o][col + 2], so[o][col + 3]);
        *(float4*)(out + ((size_t)(b * M2 + o)) * NP + n0 + col) = v;
    }
}

// ---------------------------------------------------------------------------
extern "C" void kernel_launch(void* const* d_in, const int* in_sizes, int n_in,
                              void* d_out, int out_size, void* d_ws, size_t ws_size,
                              hipStream_t stream)
{
    const float* xyz    = (const float*)d_in[0];
    const float* points = (const float*)d_in[1];
    const float* W0     = (const float*)d_in[2];
    const float* W1     = (const float*)d_in[3];
    const float* W2     = (const float*)d_in[4];
    float* out = (float*)d_out;

    char* ws = (char*)d_ws;
    float4*   pts4  = (float4*)ws;                       // 512 KB
    float4*   ptsS  = (float4*)(ws + 0x080000);          // 512 KB (pre-scaled)
    unsigned* featb = (unsigned*)(ws + 0x100000);        // 2 MB
    int*      idx   = (int*)(ws + 0x300000);             // 2 MB

    prep_kernel<<<BB * NP / 64, 256,  0, stream>>>(xyz, points, W0, pts4, ptsS, featb);
    knn_kernel <<<BB * NP / 64, 1024, 0, stream>>>(pts4, ptsS, idx);
    conv_kernel<<<BB * NP / 32, 512,  0, stream>>>(pts4, featb, idx, W0, W1, W2, out);
}

// Round 17
// 233.720 us; speedup vs baseline: 1.1919x; 1.0314x over previous
//
#include <hip/hip_runtime.h>

#define NP   8192
#define BB   4
#define DIN  32
#define M0   32
#define M1   32
#define M2   64
#define CAP  80
#define CSTR 81            // candidate row stride (odd -> conflict-free)
#define KWV  16            // waves per knn block
#define SEG  (NP / KWV)    // 512 points per wave

__device__ __forceinline__ float lrelu(float x) { return fmaxf(x, 0.1f * x); }
__device__ __forceinline__ unsigned umin_(unsigned a, unsigned b) { return a < b ? a : b; }
__device__ __forceinline__ unsigned umax_(unsigned a, unsigned b) { return a > b ? a : b; }

// monotonic float->uint key (total order incl. negatives)
__device__ __forceinline__ unsigned fkey(float f) {
    unsigned b = __float_as_uint(f);
    return (b & 0x80000000u) ? ~b : (b | 0x80000000u);
}
__device__ __forceinline__ float funkey(unsigned k) {
    unsigned b = (k & 0x80000000u) ? (k & 0x7fffffffu) : ~k;
    return __uint_as_float(b);
}

// round-to-nearest-even f32 -> bf16 (as uint16 in low bits)
__device__ __forceinline__ unsigned bf16rn(float f) {
    unsigned u = __float_as_uint(f);
    unsigned r = (u >> 16) & 1u;
    return (u + 0x7fffu + r) >> 16;
}

// max with a DPP-permuted copy: full VALU rate, no DS pipe. Row-local ops
// (quad_perm / half-mirror / mirror) -> correct 16-lane reduce for any
// aligned 16-lane group.
template<int CTRL>
__device__ __forceinline__ float fmax_dpp(float v) {
    int s = __builtin_amdgcn_update_dpp(0, __float_as_int(v), CTRL, 0xf, 0xf, true);
    return fmaxf(v, __int_as_float(s));
}

// ---------------------------------------------------------------------------
// Kernel 1: pack pts4 = (x,y,z,|p|^2), ptsS = (-2x,-2y,-2z,|p|^2) and
// feat = W0[:,3:] @ points stored as bf16 pairs. Block = 4 waves over the
// same 64 points; wave w computes outputs [8w, 8w+8).
// ---------------------------------------------------------------------------
__global__ __launch_bounds__(256) void prep_kernel(
    const float* __restrict__ xyz, const float* __restrict__ points,
    const float* __restrict__ W0, float4* __restrict__ pts4,
    float4* __restrict__ ptsS, unsigned* __restrict__ featb)
{
    const int tid  = threadIdx.x;
    const int w    = __builtin_amdgcn_readfirstlane(tid >> 6);  // 0..3
    const int lane = tid & 63;
    const int t    = blockIdx.x * 64 + lane;     // point id, 512 blocks
    const int b    = t >> 13;
    const int n    = t & (NP - 1);

    if (w == 0) {
        const float* xb = xyz + (size_t)b * 3 * NP;
        float x = xb[n], y = xb[NP + n], z = xb[2 * NP + n];
        float s = x * x + y * y + z * z;
        pts4[t] = make_float4(x, y, z, s);
        ptsS[t] = make_float4(-2.f * x, -2.f * y, -2.f * z, s);
    }

    const float* pb = points + (size_t)b * DIN * NP + n;
    float p[DIN];
#pragma unroll
    for (int c = 0; c < DIN; ++c) p[c] = pb[c * NP];

    uint4 outv;
    unsigned* ov = (unsigned*)&outv;
#pragma unroll
    for (int r = 0; r < 4; ++r) {
        int oe = w * 8 + 2 * r;
        float a0 = 0.f, a1 = 0.f;
#pragma unroll
        for (int c = 0; c < DIN; ++c) {
            a0 = fmaf(W0[oe * 35 + 3 + c], p[c], a0);
            a1 = fmaf(W0[(oe + 1) * 35 + 3 + c], p[c], a1);
        }
        ov[r] = bf16rn(a0) | (bf16rn(a1) << 16);
    }
    *(uint4*)(featb + (size_t)t * 16 + w * 4) = outv;
}

// ---------------------------------------------------------------------------
// Kernel 2: exact 16-NN via scalar-pipe query broadcast. Single 512-block
// dispatch (r15 proved splitting costs ~85us: knn is intra-block
// latency-bound, not machine-throughput-bound). lane = point; 8 pre-scaled
// points/lane in registers; queries s_loaded in chunks of 8, fed to v_fma
// as SGPR operands.
// ---------------------------------------------------------------------------
__global__ __launch_bounds__(1024, 4) void knn_kernel(const float4* __restrict__ pts4,
                                                      const float4* __restrict__ ptsS,
                                                      int* __restrict__ idxout)
{
    __shared__ unsigned skey[64 * 65];              // 16.6 KB class-min keys
    __shared__ float    sT[64];
    __shared__ int      scnt[64];
    __shared__ float    cand_t[64 * CSTR];          // 20.7 KB
    __shared__ int      cand_i[64 * CSTR];          // 20.7 KB

    const int tid  = threadIdx.x;
    const int w    = __builtin_amdgcn_readfirstlane(tid >> 6);
    const int lane = tid & 63;
    const int blk  = blockIdx.x;           // 512 blocks
    const int b    = blk >> 7;
    const int n0   = (blk & 127) << 6;
    const int bn0  = b * NP;
    const float4* P  = pts4 + bn0;         // raw (queries, fallback)
    const float4* S  = ptsS + bn0;         // pre-scaled (scan points)
    const float4* Pq = P + n0;             // this block's 64 queries

    for (int i = tid; i < 64 * 65; i += 1024) skey[i] = 0xFFFFFFFFu;
    if (tid < 64) scnt[tid] = 0;
    __syncthreads();

    // ---- load my 8 pre-scaled points once (coalesced, register-resident) ----
    const int base = w * SEG;
    float4 sp[8];
#pragma unroll
    for (int j = 0; j < 8; ++j) sp[j] = S[base + j * 64 + lane];

    // ---- pass 1: chunks of 8 queries via s_load; min3-tree over 8 pts ----
#pragma unroll 1
    for (int qc = 0; qc < 8; ++qc) {
        float4 qv[8];
#pragma unroll
        for (int i = 0; i < 8; ++i) qv[i] = Pq[qc * 8 + i];   // uniform -> s_load
#pragma unroll
        for (int i = 0; i < 8; ++i) {
            const float qx = qv[i].x, qy = qv[i].y, qz = qv[i].z;
            float t[8];
#pragma unroll
            for (int j = 0; j < 8; ++j)
                t[j] = fmaf(qx, sp[j].x, fmaf(qy, sp[j].y, fmaf(qz, sp[j].z, sp[j].w)));
            float a = fminf(fminf(t[0], t[1]), t[2]);   // v_min3
            float b2 = fminf(fminf(t[3], t[4]), t[5]);  // v_min3
            float c2 = fminf(fminf(t[6], t[7]), a);     // v_min3
            float mn = fminf(b2, c2);
            atomicMin(&skey[(qc * 8 + i) * 65 + lane], fkey(mn));
        }
    }
    __syncthreads();

    // ---- threshold: 16th smallest of the 64 class minima (thread = query) ----
    if (tid < 64) {
        unsigned t16[16];
#pragma unroll
        for (int i = 0; i < 16; ++i) t16[i] = 0xFFFFFFFFu;
        for (int c = 0; c < 64; ++c) {
            unsigned d = skey[tid * 65 + c];
            if (d < t16[15]) {
                t16[15] = d;
#pragma unroll
                for (int i = 15; i > 0; --i) {
                    unsigned a = t16[i - 1], cc = t16[i];
                    t16[i - 1] = umin_(a, cc);
                    t16[i]     = umax_(a, cc);
                }
            }
        }
        sT[tid] = funkey(t16[15]);
    }
    __syncthreads();

    // ---- pass 2: bit-identical recompute, per-point t<=T append ----
#pragma unroll 1
    for (int qc = 0; qc < 8; ++qc) {
        float4 qv[8];
#pragma unroll
        for (int i = 0; i < 8; ++i) qv[i] = Pq[qc * 8 + i];   // uniform -> s_load
#pragma unroll
        for (int i = 0; i < 8; ++i) {
            const int q = qc * 8 + i;
            const float qx = qv[i].x, qy = qv[i].y, qz = qv[i].z;
            const float T = sT[q];
#pragma unroll
            for (int j = 0; j < 8; ++j) {
                float t = fmaf(qx, sp[j].x, fmaf(qy, sp[j].y, fmaf(qz, sp[j].z, sp[j].w)));
                if (t <= T) {                        // ~16% wave-prob per point
                    int pos = atomicAdd(&scnt[q], 1);
                    if (pos < CAP) {
                        cand_t[q * CSTR + pos] = t;
                        cand_i[q * CSTR + pos] = base + j * 64 + lane;
                    }
                }
            }
        }
    }
    __syncthreads();

    // ---- exact selection among candidates (thread = query) ----
    if (tid < 64) {
        int cnt = scnt[tid];
        int* outp = idxout + ((bn0 + n0 + tid) << 4);
        float bd[16]; int bi[16];
#pragma unroll
        for (int i = 0; i < 16; ++i) { bd[i] = 3e38f; bi[i] = 0; }
        if (cnt <= CAP) {
            for (int pos = 0; pos < cnt; ++pos) {
                float d = cand_t[tid * CSTR + pos];
                int   j = cand_i[tid * CSTR + pos];
                if ((d < bd[15]) || (d == bd[15] && j < bi[15])) {
                    bd[15] = d; bi[15] = j;
#pragma unroll
                    for (int i = 15; i > 0; --i) {
                        bool sw = (bd[i] < bd[i - 1]) || (bd[i] == bd[i - 1] && bi[i] < bi[i - 1]);
                        float td = bd[i - 1]; int tj = bi[i - 1];
                        bd[i - 1] = sw ? bd[i] : td;  bi[i - 1] = sw ? bi[i] : tj;
                        bd[i]     = sw ? td : bd[i];  bi[i]     = sw ? tj : bi[i];
                    }
                }
            }
        } else {
            // overflow fallback (exact, never expected): identical fma form
            float4 q4 = Pq[tid];
            for (int j = 0; j < NP; ++j) {
                float4 s = S[j];
                float d = fmaf(q4.x, s.x, fmaf(q4.y, s.y, fmaf(q4.z, s.z, s.w)));
                if ((d < bd[15]) || (d == bd[15] && j < bi[15])) {
                    bd[15] = d; bi[15] = j;
#pragma unroll
                    for (int i = 15; i > 0; --i) {
                        bool sw = (bd[i] < bd[i - 1]) || (bd[i] == bd[i - 1] && bi[i] < bi[i - 1]);
                        float td = bd[i - 1]; int tj = bi[i - 1];
                        bd[i - 1] = sw ? bd[i] : td;  bi[i - 1] = sw ? bi[i] : tj;
                        bd[i]     = sw ? td : bd[i];  bi[i]     = sw ? tj : bi[i];
                    }
                }
            }
        }
#pragma unroll
        for (int i = 0; i < 16; ++i) outp[i] = bi[i];
    }
}

// ---------------------------------------------------------------------------
// Kernel 3: gather + conv0/1/2 + max over K. EXACTLY the r15-measured best:
// one thread per (n,k), 256-thread blocks (16 n x 16 k), 2048 blocks, plain
// __launch_bounds__(256) (no min-wave cap: (256,4) cost ~30%; 512-thread
// blocks in r16 cost ~45us — both measured regressions). bf16 feat gather,
// DPP k-max. r15 counters: 77-81us, VGPR 36, WRITE 8MB (no spill),
// VALUBusy ~73% — near the fp32 issue floor.
// ---------------------------------------------------------------------------
__global__ __launch_bounds__(256) void conv_kernel(
    const float4* __restrict__ pts4, const unsigned* __restrict__ featb,
    const int* __restrict__ idx,
    const float* __restrict__ W0, const float* __restrict__ W1, const float* __restrict__ W2,
    float* __restrict__ out)
{
    __shared__ float so[M2][17];
    const int tid = threadIdx.x;
    const int k   = tid & 15;
    const int nl  = tid >> 4;              // 0..15
    const int blk = blockIdx.x;            // 2048 blocks
    const int b   = blk >> 9;              // 512 blocks per batch
    const int n0  = (blk & 511) << 4;
    const int n   = n0 + nl;
    const int bn  = b * NP + n;
    const int j   = idx[(bn << 4) + k];
    const int bj  = b * NP + j;

    const float4 pc = pts4[bn];
    const float4 pj = pts4[bj];
    const float rx = pj.x - pc.x, ry = pj.y - pc.y, rz = pj.z - pc.z;

    const uint4* fj = (const uint4*)(featb + (size_t)bj * 16);

    float x0[M0];
#pragma unroll
    for (int g = 0; g < 4; ++g) {
        uint4 u = fj[g];
        const unsigned* uv = (const unsigned*)&u;
#pragma unroll
        for (int r = 0; r < 4; ++r) {
            int o = g * 8 + 2 * r;
            float fe  = __uint_as_float(uv[r] << 16);
            float fo_ = __uint_as_float(uv[r] & 0xffff0000u);
            x0[o]     = lrelu(fmaf(W0[o * 35], rx, fmaf(W0[o * 35 + 1], ry, fmaf(W0[o * 35 + 2], rz, fe))));
            x0[o + 1] = lrelu(fmaf(W0[(o + 1) * 35], rx, fmaf(W0[(o + 1) * 35 + 1], ry, fmaf(W0[(o + 1) * 35 + 2], rz, fo_))));
        }
    }

    float x1[M1];
#pragma unroll
    for (int o = 0; o < M1; ++o) {
        float acc = 0.f;
#pragma unroll
        for (int c = 0; c < M0; ++c) acc = fmaf(W1[o * 32 + c], x0[c], acc);
        x1[o] = lrelu(acc);
    }

#pragma unroll
    for (int o = 0; o < M2; ++o) {
        float acc = 0.f;
#pragma unroll
        for (int c = 0; c < M1; ++c) acc = fmaf(W2[o * 32 + c], x1[c], acc);
        float v = lrelu(acc);
        // 16-lane max reduce via DPP (VALU-rate, no DS):
        v = fmax_dpp<0xB1>(v);    // quad_perm xor1
        v = fmax_dpp<0x4E>(v);    // quad_perm xor2
        v = fmax_dpp<0x141>(v);   // row_half_mirror
        v = fmax_dpp<0x140>(v);   // row_mirror
        if (k == (o & 15)) so[o][nl] = v;
    }
    __syncthreads();
    {
        int o = tid >> 2;                 // 0..63
        int col = (tid & 3) << 2;         // 0,4,8,12
        float4 v = make_float4(so[o][col], so[o][col + 1], so[o][col + 2], so[o][col + 3]);
        *(float4*)(out + ((size_t)(b * M2 + o)) * NP + n0 + col) = v;
    }
}

// ---------------------------------------------------------------------------
extern "C" void kernel_launch(void* const* d_in, const int* in_sizes, int n_in,
                              void* d_out, int out_size, void* d_ws, size_t ws_size,
                              hipStream_t stream)
{
    const float* xyz    = (const float*)d_in[0];
    const float* points = (const float*)d_in[1];
    const float* W0     = (const float*)d_in[2];
    const float* W1     = (const float*)d_in[3];
    const float* W2     = (const float*)d_in[4];
    float* out = (float*)d_out;

    char* ws = (char*)d_ws;
    float4*   pts4  = (float4*)ws;                       // 512 KB
    float4*   ptsS  = (float4*)(ws + 0x080000);          // 512 KB (pre-scaled)
    unsigned* featb = (unsigned*)(ws + 0x100000);        // 2 MB
    int*      idx   = (int*)(ws + 0x300000);             // 2 MB

    prep_kernel<<<BB * NP / 64, 256,  0, stream>>>(xyz, points, W0, pts4, ptsS, featb);
    knn_kernel <<<BB * NP / 64, 1024, 0, stream>>>(pts4, ptsS, idx);
    conv_kernel<<<BB * NP / 16, 256,  0, stream>>>(pts4, featb, idx, W0, W1, W2, out);
}